// Round 4
// baseline (212.831 us; speedup 1.0000x reference)
//
#include <hip/hip_runtime.h>
#include <stdint.h>

#define B_    16
#define FIN   256
#define FOUT  256
#define FH2   256
#define NMIX  8
#define LAT   512
#define HW    4096
#define MT    64

typedef short bf16x8 __attribute__((ext_vector_type(8)));
typedef float f32x4  __attribute__((ext_vector_type(4)));

// workspace layout (bytes) -- unchanged
#define WS_MIX    0           // [16][8] f32
#define WS_BIAS   1024        // [4][16][256] f32 : in, mid, out, short
#define WS_WIN    131072      // [16][65536] bf16, fragment-packed
#define WS_WMID   2228224     // [16][131072] bf16, fragment-packed (sin/cos interleaved k')
#define WS_WOUT   6422528     // [16][131072] bf16, fragment-packed
#define WS_WSHORT 10616832    // [16][65536] bf16, fragment-packed

__device__ __forceinline__ uint16_t f2bf(float f) {
  uint32_t u = __builtin_bit_cast(uint32_t, f);
  u += 0x7fffu + ((u >> 16) & 1u);
  return (uint16_t)(u >> 16);
}
__device__ __forceinline__ uint32_t pack2(float lo, float hi) {
  return (uint32_t)f2bf(lo) | ((uint32_t)f2bf(hi) << 16);
}

#define MFMA(a, b, c) __builtin_amdgcn_mfma_f32_16x16x32_bf16(a, b, c, 0, 0, 0)

// ---------------- kernel A: mix + biases (one block per sample) ----------------
__global__ void k_mix_bias(const float* __restrict__ lat,
                           const float* __restrict__ w_dyna,
                           const float* __restrict__ b_dyna,
                           const float* __restrict__ b_in_mix,
                           const float* __restrict__ b_mid_mix,
                           const float* __restrict__ b_out_mix,
                           const float* __restrict__ b_short_mix,
                           float* __restrict__ ws_mix,
                           float* __restrict__ ws_bias) {
  __shared__ float smix[NMIX];
  const int t = threadIdx.x;
  const int lane = t & 63, wv = t >> 6;
  const int b = blockIdx.x;
#pragma unroll
  for (int d2 = 0; d2 < 2; d2++) {
    int m = wv * 2 + d2;
    float s = 0.f;
#pragma unroll
    for (int j = 0; j < 8; j++)
      s += lat[b * LAT + j * 64 + lane] * w_dyna[m * LAT + j * 64 + lane];
#pragma unroll
    for (int off = 32; off; off >>= 1) s += __shfl_xor(s, off);
    if (lane == 0) {
      float v = s + b_dyna[m];
      ws_mix[b * NMIX + m] = v;
      smix[m] = v;
    }
  }
  __syncthreads();
  const float* banks[4] = {b_in_mix, b_mid_mix, b_out_mix, b_short_mix};
  for (int pos = t; pos < 1024; pos += 256) {
    int bank = pos >> 8, ch = pos & 255;
    const float* bp = banks[bank];
    float a = 0.f;
#pragma unroll
    for (int m = 0; m < NMIX; m++) a += smix[m] * bp[m * 256 + ch];
    ws_bias[(bank * B_ + b) * 256 + ch] = a;
  }
}

// ---------------- kernel B: mixed per-sample bf16 weights, FRAGMENT-PACKED ----
// (unchanged from round 3 -- passed, bit-identical packed layout)
__global__ void k_weights(const float* __restrict__ k_in_mix,
                          const float* __restrict__ k_mid_mix,
                          const float* __restrict__ k_out_mix,
                          const float* __restrict__ k_short_mix,
                          const float* __restrict__ ws_mix,
                          uint16_t* __restrict__ w_in,
                          uint16_t* __restrict__ w_mid,
                          uint16_t* __restrict__ w_out,
                          uint16_t* __restrict__ w_short) {
  __shared__ float smix[B_ * NMIX];
  const int t = threadIdx.x;
  if (t < B_ * NMIX) smix[t] = ws_mix[t];
  __syncthreads();
  const int e8 = (blockIdx.x * 256 + t) * 8;  // 8-aligned packed position
  const float* srcA;
  uint16_t* dst;
  int sstride, dstride;
  bool ileave;  // block-uniform
  if (e8 < 65536) {                       // w_in, KT=8
    int e = e8;
    int lane = (e >> 3) & 63, ots = (e >> 9) & 3, kt = (e >> 11) & 7, wv = e >> 14;
    int row = wv * 64 + ots * 16 + (lane & 15);
    int k0 = kt * 32 + (lane >> 4) * 8;
    srcA = k_in_mix + row * 256 + k0; sstride = 65536; ileave = false;
    dst = w_in + e;                   dstride = 65536;
  } else if (e8 < 196608) {               // w_mid, KT=16, sin/cos interleave
    int e = e8 - 65536;
    int lane = (e >> 3) & 63, ots = (e >> 9) & 3, kt = (e >> 11) & 15, wv = e >> 15;
    int row = wv * 64 + ots * 16 + (lane & 15);
    int kp0 = kt * 32 + (lane >> 4) * 8;       // 8-aligned -> i0 = kp0/2, 4-aligned
    srcA = k_mid_mix + row * 512 + (kp0 >> 1); sstride = 131072; ileave = true;
    dst = w_mid + e;                           dstride = 131072;
  } else if (e8 < 327680) {               // w_out, KT=16, interleave
    int e = e8 - 196608;
    int lane = (e >> 3) & 63, ots = (e >> 9) & 3, kt = (e >> 11) & 15, wv = e >> 15;
    int row = wv * 64 + ots * 16 + (lane & 15);
    int kp0 = kt * 32 + (lane >> 4) * 8;
    srcA = k_out_mix + row * 512 + (kp0 >> 1); sstride = 131072; ileave = true;
    dst = w_out + e;                           dstride = 131072;
  } else {                                // w_short, KT=8
    int e = e8 - 327680;
    int lane = (e >> 3) & 63, ots = (e >> 9) & 3, kt = (e >> 11) & 7, wv = e >> 14;
    int row = wv * 64 + ots * 16 + (lane & 15);
    int k0 = kt * 32 + (lane >> 4) * 8;
    srcA = k_short_mix + row * 256 + k0; sstride = 65536; ileave = false;
    dst = w_short + e;                   dstride = 65536;
  }
  // srcB offset: non-interleaved -> +4 (elements 4..7); interleaved -> +256 (cos half)
  const int boff = ileave ? 256 : 4;
  float4 va[NMIX], vb[NMIX];
#pragma unroll
  for (int m = 0; m < NMIX; m++) {
    va[m] = *(const float4*)(srcA + m * sstride);
    vb[m] = *(const float4*)(srcA + m * sstride + boff);
  }
  for (int b = 0; b < B_; b++) {
    float4 ra = make_float4(0.f, 0.f, 0.f, 0.f), rb = ra;
#pragma unroll
    for (int m = 0; m < NMIX; m++) {
      const float s = smix[b * NMIX + m];
      ra.x += s * va[m].x; ra.y += s * va[m].y; ra.z += s * va[m].z; ra.w += s * va[m].w;
      rb.x += s * vb[m].x; rb.y += s * vb[m].y; rb.z += s * vb[m].z; rb.w += s * vb[m].w;
    }
    int4 pkt;
    if (ileave) {  // out order: a0,b0,a1,b1,a2,b2,a3,b3  (sin/cos interleave)
      pkt = make_int4((int)pack2(ra.x, rb.x), (int)pack2(ra.y, rb.y),
                      (int)pack2(ra.z, rb.z), (int)pack2(ra.w, rb.w));
    } else {       // out order: a0,a1,a2,a3,b0,b1,b2,b3
      pkt = make_int4((int)pack2(ra.x, ra.y), (int)pack2(ra.z, ra.w),
                      (int)pack2(rb.x, rb.y), (int)pack2(rb.z, rb.w));
    }
    *(int4*)(dst + (size_t)b * dstride) = pkt;
  }
}

// ---------------- main fused kernel (v4) ----
// vs v3:
//  (1) phase A: 64-channel X chunks = 2 kt-steps per chunk -> barrier (and its
//      vmcnt drain) every 2 steps instead of every step; chunk c+1 global loads
//      issue at chunk-c top -> ~2 MFMA clusters of real latency cover.
//  (2) phases B/C: explicit ds_read ping-pong (fragment kt+1 loaded before
//      cluster kt) -> MFMA cluster never waits on fresh lgkm.
//  (3) plain __syncthreads only (no novel sync primitives).
// LDS 80KB -> 2 blocks/CU: Xc 2 x 8KB double-buffer, H1 64KB (H2 overlays).
__launch_bounds__(256, 2)
__global__ void k_main(const float* __restrict__ x,
                       const float* __restrict__ ws_bias,
                       const uint16_t* __restrict__ w_in,
                       const uint16_t* __restrict__ w_mid,
                       const uint16_t* __restrict__ w_out,
                       const uint16_t* __restrict__ w_short,
                       float* __restrict__ out) {
  __shared__ int4 smem4[81920 / 16];
  char* lds = (char*)smem4;
  char* Xc = lds;            // 2 x 8192 bytes (64ch x 64pos bf16 each)
  char* H1 = lds + 16384;    // 65536 bytes (H2 overlays after barrier)

  const int t = threadIdx.x;
  const int lane = t & 63;
  const int wv = t >> 6;     // 0..3
  const int q = lane >> 4;
  const int n = lane & 15;
  const int b = blockIdx.x & 15;
  const int p0 = (blockIdx.x >> 4) * MT;

  const float* xb = x + (size_t)b * FIN * HW + p0;
  const int xpos = t & 63;   // position this thread stages

  // ---- stage X chunk 0 (channels 0..63) into buf 0 ----
  float xv[2][8];
#pragma unroll
  for (int u = 0; u < 2; u++) {
    const int cg = wv * 2 + u;  // 0..7 (8-channel groups within chunk)
#pragma unroll
    for (int e = 0; e < 8; e++)
      xv[u][e] = xb[(size_t)(cg * 8 + e) * HW + xpos];
  }
#pragma unroll
  for (int u = 0; u < 2; u++) {
    const int cg = wv * 2 + u;
    *(int4*)(Xc + xpos * 128 + ((cg ^ (xpos & 7)) * 16)) =
        make_int4((int)pack2(xv[u][0], xv[u][1]), (int)pack2(xv[u][2], xv[u][3]),
                  (int)pack2(xv[u][4], xv[u][5]), (int)pack2(xv[u][6], xv[u][7]));
  }

  // ---- phase A accumulator init: h = b_in, s = b_short ----
  f32x4 acc_h[4][4], acc_s[4][4];
#pragma unroll
  for (int ots = 0; ots < 4; ots++) {
    const int o = wv * 64 + ots * 16 + q * 4;
    const float4 vi = *(const float4*)&ws_bias[(0 * B_ + b) * 256 + o];
    const float4 vs = *(const float4*)&ws_bias[(3 * B_ + b) * 256 + o];
    f32x4 ah, asv;
    ah[0] = vi.x; ah[1] = vi.y; ah[2] = vi.z; ah[3] = vi.w;
    asv[0] = vs.x; asv[1] = vs.y; asv[2] = vs.z; asv[3] = vs.w;
#pragma unroll
    for (int pt = 0; pt < 4; pt++) { acc_h[ots][pt] = ah; acc_s[ots][pt] = asv; }
  }

  // phase-A weight prefetch (kt=0), issued before the barrier
  const uint16_t* Wi = w_in + (size_t)b * 65536 + wv * 16384 + lane * 8;
  const uint16_t* Ws = w_short + (size_t)b * 65536 + wv * 16384 + lane * 8;
  bf16x8 ai[2][4], asf[2][4];
#pragma unroll
  for (int ots = 0; ots < 4; ots++) {
    ai[0][ots] = *(const bf16x8*)(Wi + ots * 512);
    asf[0][ots] = *(const bf16x8*)(Ws + ots * 512);
  }
  __syncthreads();

  // ---- phase A: h1 = K_in @ X + b_in ; short = K_short @ X + b_short ----
  // chunk c holds channels c*64..c*64+63 = kt-steps {2c, 2c+1}; barrier only
  // at chunk boundaries, so chunk c+1's loads get ~2 MFMA clusters of cover.
#pragma unroll
  for (int c = 0; c < 4; c++) {
    if (c < 3) {  // issue next chunk's global loads first
#pragma unroll
      for (int u = 0; u < 2; u++) {
        const int cg = wv * 2 + u;
#pragma unroll
        for (int e = 0; e < 8; e++)
          xv[u][e] = xb[(size_t)((c + 1) * 64 + cg * 8 + e) * HW + xpos];
      }
    }
    const char* Xr = Xc + (c & 1) * 8192;
#pragma unroll
    for (int lh = 0; lh < 2; lh++) {
      const int kt = c * 2 + lh;
      if (kt < 7) {  // 1-ahead weight prefetch (survives within chunk)
#pragma unroll
        for (int ots = 0; ots < 4; ots++) {
          ai[(kt + 1) & 1][ots] = *(const bf16x8*)(Wi + (kt + 1) * 2048 + ots * 512);
          asf[(kt + 1) & 1][ots] = *(const bf16x8*)(Ws + (kt + 1) * 2048 + ots * 512);
        }
      }
      bf16x8 bf[4];
#pragma unroll
      for (int pt = 0; pt < 4; pt++) {
        const int p = pt * 16 + n;
        bf[pt] = *(const bf16x8*)(Xr + p * 128 + (((lh * 4 + q) ^ (p & 7)) * 16));
      }
      __builtin_amdgcn_s_setprio(1);
#pragma unroll
      for (int ots = 0; ots < 4; ots++) {
#pragma unroll
        for (int pt = 0; pt < 4; pt++) {
          acc_h[ots][pt] = MFMA(ai[kt & 1][ots], bf[pt], acc_h[ots][pt]);
          acc_s[ots][pt] = MFMA(asf[kt & 1][ots], bf[pt], acc_s[ots][pt]);
        }
      }
      __builtin_amdgcn_s_setprio(0);
    }
    if (c < 3) {
#pragma unroll
      for (int u = 0; u < 2; u++) {
        const int cg = wv * 2 + u;
        *(int4*)(Xc + ((c + 1) & 1) * 8192 + xpos * 128 + ((cg ^ (xpos & 7)) * 16)) =
            make_int4((int)pack2(xv[u][0], xv[u][1]), (int)pack2(xv[u][2], xv[u][3]),
                      (int)pack2(xv[u][4], xv[u][5]), (int)pack2(xv[u][6], xv[u][7]));
      }
      __syncthreads();  // protects X double-buffer (every 2 kt-steps)
    }
  }

  // ---- complex_wave(h1) -> H1 (k' = 2*o + {0:sin,1:cos}, ctile-xor swizzle) ----
#pragma unroll
  for (int ots = 0; ots < 4; ots++) {
    const int ctile = (wv * 4 + ots) * 4 + q;
#pragma unroll
    for (int pt = 0; pt < 4; pt++) {
      const int p = pt * 16 + n;
      *(int4*)(H1 + p * 1024 + ((ctile ^ (p & 7)) * 16)) = make_int4(
          (int)pack2(__sinf(acc_h[ots][pt][0]), __cosf(acc_h[ots][pt][0])),
          (int)pack2(__sinf(acc_h[ots][pt][1]), __cosf(acc_h[ots][pt][1])),
          (int)pack2(__sinf(acc_h[ots][pt][2]), __cosf(acc_h[ots][pt][2])),
          (int)pack2(__sinf(acc_h[ots][pt][3]), __cosf(acc_h[ots][pt][3])));
    }
  }

  // phase-B prologue: bias init + 3-deep weight prefetch, before the barrier
  const uint16_t* Wm = w_mid + (size_t)b * 131072 + wv * 32768 + lane * 8;
  bf16x8 am[4][4];
#pragma unroll
  for (int ots = 0; ots < 4; ots++) {
    am[0][ots] = *(const bf16x8*)(Wm + 0 * 2048 + ots * 512);
    am[1][ots] = *(const bf16x8*)(Wm + 1 * 2048 + ots * 512);
    am[2][ots] = *(const bf16x8*)(Wm + 2 * 2048 + ots * 512);
  }
  f32x4 acc2[4][4];
#pragma unroll
  for (int ots = 0; ots < 4; ots++) {
    const int o = wv * 64 + ots * 16 + q * 4;
    const float4 v = *(const float4*)&ws_bias[(1 * B_ + b) * 256 + o];
    f32x4 a2;
    a2[0] = v.x; a2[1] = v.y; a2[2] = v.z; a2[3] = v.w;
#pragma unroll
    for (int pt = 0; pt < 4; pt++) acc2[ots][pt] = a2;
  }
  __syncthreads();  // H1 writes visible to all waves

  // ---- phase B: h2 = K_mid(perm) @ H1c + b_mid (barrier-free, ds ping-pong) ----
  {
    bf16x8 bfB[2][4];
#pragma unroll
    for (int pt = 0; pt < 4; pt++) {
      const int p = pt * 16 + n;
      bfB[0][pt] = *(const bf16x8*)(H1 + p * 1024 + ((q ^ (p & 7)) * 16));
    }
#pragma unroll
    for (int kt = 0; kt < 16; kt++) {
      if (kt < 15) {  // load fragment kt+1 before cluster kt
#pragma unroll
        for (int pt = 0; pt < 4; pt++) {
          const int p = pt * 16 + n;
          bfB[(kt + 1) & 1][pt] =
              *(const bf16x8*)(H1 + p * 1024 + ((((kt + 1) * 4 + q) ^ (p & 7)) * 16));
        }
      }
      if (kt < 13) {
#pragma unroll
        for (int ots = 0; ots < 4; ots++)
          am[(kt + 3) & 3][ots] = *(const bf16x8*)(Wm + (kt + 3) * 2048 + ots * 512);
      }
      __builtin_amdgcn_s_setprio(1);
#pragma unroll
      for (int ots = 0; ots < 4; ots++)
#pragma unroll
        for (int pt = 0; pt < 4; pt++)
          acc2[ots][pt] = MFMA(am[kt & 3][ots], bfB[kt & 1][pt], acc2[ots][pt]);
      __builtin_amdgcn_s_setprio(0);
    }
  }
  __syncthreads();  // all H1 reads done before overwrite

  // ---- complex_wave(h2) -> H2 (overlays H1 region) ----
#pragma unroll
  for (int ots = 0; ots < 4; ots++) {
    const int ctile = (wv * 4 + ots) * 4 + q;
#pragma unroll
    for (int pt = 0; pt < 4; pt++) {
      const int p = pt * 16 + n;
      *(int4*)(H1 + p * 1024 + ((ctile ^ (p & 7)) * 16)) = make_int4(
          (int)pack2(__sinf(acc2[ots][pt][0]), __cosf(acc2[ots][pt][0])),
          (int)pack2(__sinf(acc2[ots][pt][1]), __cosf(acc2[ots][pt][1])),
          (int)pack2(__sinf(acc2[ots][pt][2]), __cosf(acc2[ots][pt][2])),
          (int)pack2(__sinf(acc2[ots][pt][3]), __cosf(acc2[ots][pt][3])));
    }
  }

  // phase-C prologue: acc3 = short + b_out (in place in acc_s) + 3-deep prefetch
  const uint16_t* Wo = w_out + (size_t)b * 131072 + wv * 32768 + lane * 8;
  bf16x8 ao[4][4];
#pragma unroll
  for (int ots = 0; ots < 4; ots++) {
    ao[0][ots] = *(const bf16x8*)(Wo + 0 * 2048 + ots * 512);
    ao[1][ots] = *(const bf16x8*)(Wo + 1 * 2048 + ots * 512);
    ao[2][ots] = *(const bf16x8*)(Wo + 2 * 2048 + ots * 512);
  }
#pragma unroll
  for (int ots = 0; ots < 4; ots++) {
    const int o = wv * 64 + ots * 16 + q * 4;
    const float4 v = *(const float4*)&ws_bias[(2 * B_ + b) * 256 + o];
#pragma unroll
    for (int pt = 0; pt < 4; pt++) {
      acc_s[ots][pt][0] += v.x; acc_s[ots][pt][1] += v.y;
      acc_s[ots][pt][2] += v.z; acc_s[ots][pt][3] += v.w;
    }
  }
  __syncthreads();  // H2 writes visible

  // ---- phase C: out = K_out(perm) @ H2c + b_out + short (ds ping-pong) ----
  {
    bf16x8 bfC[2][4];
#pragma unroll
    for (int pt = 0; pt < 4; pt++) {
      const int p = pt * 16 + n;
      bfC[0][pt] = *(const bf16x8*)(H1 + p * 1024 + ((q ^ (p & 7)) * 16));
    }
#pragma unroll
    for (int kt = 0; kt < 16; kt++) {
      if (kt < 15) {
#pragma unroll
        for (int pt = 0; pt < 4; pt++) {
          const int p = pt * 16 + n;
          bfC[(kt + 1) & 1][pt] =
              *(const bf16x8*)(H1 + p * 1024 + ((((kt + 1) * 4 + q) ^ (p & 7)) * 16));
        }
      }
      if (kt < 13) {
#pragma unroll
        for (int ots = 0; ots < 4; ots++)
          ao[(kt + 3) & 3][ots] = *(const bf16x8*)(Wo + (kt + 3) * 2048 + ots * 512);
      }
      __builtin_amdgcn_s_setprio(1);
#pragma unroll
      for (int ots = 0; ots < 4; ots++)
#pragma unroll
        for (int pt = 0; pt < 4; pt++)
          acc_s[ots][pt] = MFMA(ao[kt & 3][ots], bfC[kt & 1][pt], acc_s[ots][pt]);
      __builtin_amdgcn_s_setprio(0);
    }
  }

  // ---- store ----
  {
    float* ob = out + (size_t)b * FOUT * HW + p0;
#pragma unroll
    for (int ots = 0; ots < 4; ots++) {
#pragma unroll
      for (int pt = 0; pt < 4; pt++) {
#pragma unroll
        for (int r = 0; r < 4; r++) {
          const int o = wv * 64 + ots * 16 + q * 4 + r;
          ob[(size_t)o * HW + pt * 16 + n] = acc_s[ots][pt][r];
        }
      }
    }
  }
}

extern "C" void kernel_launch(void* const* d_in, const int* in_sizes, int n_in,
                              void* d_out, int out_size, void* d_ws, size_t ws_size,
                              hipStream_t stream) {
  const float* x           = (const float*)d_in[0];
  const float* lat         = (const float*)d_in[1];
  const float* k_in_mix    = (const float*)d_in[2];
  const float* k_mid_mix   = (const float*)d_in[3];
  const float* k_out_mix   = (const float*)d_in[4];
  const float* k_short_mix = (const float*)d_in[5];
  const float* b_in_mix    = (const float*)d_in[6];
  const float* b_mid_mix   = (const float*)d_in[7];
  const float* b_out_mix   = (const float*)d_in[8];
  const float* b_short_mix = (const float*)d_in[9];
  const float* w_dyna      = (const float*)d_in[10];
  const float* b_dyna      = (const float*)d_in[11];

  char* ws = (char*)d_ws;
  float*    ws_mix  = (float*)(ws + WS_MIX);
  float*    ws_bias = (float*)(ws + WS_BIAS);
  uint16_t* w_in    = (uint16_t*)(ws + WS_WIN);
  uint16_t* w_mid   = (uint16_t*)(ws + WS_WMID);
  uint16_t* w_out   = (uint16_t*)(ws + WS_WOUT);
  uint16_t* w_short = (uint16_t*)(ws + WS_WSHORT);
  float* out = (float*)d_out;

  hipLaunchKernelGGL(k_mix_bias, dim3(16), dim3(256), 0, stream,
                     lat, w_dyna, b_dyna, b_in_mix, b_mid_mix, b_out_mix,
                     b_short_mix, ws_mix, ws_bias);
  hipLaunchKernelGGL(k_weights, dim3(192), dim3(256), 0, stream,
                     k_in_mix, k_mid_mix, k_out_mix, k_short_mix, ws_mix,
                     w_in, w_mid, w_out, w_short);
  hipLaunchKernelGGL(k_main, dim3(1024), dim3(256), 0, stream,
                     x, ws_bias, w_in, w_mid, w_out, w_short, out);
}

// Round 5
// 190.342 us; speedup vs baseline: 1.1181x; 1.1181x over previous
//
#include <hip/hip_runtime.h>
#include <stdint.h>

#define B_    16
#define FIN   256
#define FOUT  256
#define FH2   256
#define NMIX  8
#define LAT   512
#define HW    4096
#define MT    64

typedef short bf16x8 __attribute__((ext_vector_type(8)));
typedef float f32x4  __attribute__((ext_vector_type(4)));

// workspace layout (bytes) -- unchanged
#define WS_MIX    0           // [16][8] f32
#define WS_BIAS   1024        // [4][16][256] f32 : in, mid, out, short
#define WS_WIN    131072      // [16][65536] bf16, fragment-packed
#define WS_WMID   2228224     // [16][131072] bf16, fragment-packed (sin/cos interleaved k')
#define WS_WOUT   6422528     // [16][131072] bf16, fragment-packed
#define WS_WSHORT 10616832    // [16][65536] bf16, fragment-packed

__device__ __forceinline__ uint16_t f2bf(float f) {
  uint32_t u = __builtin_bit_cast(uint32_t, f);
  u += 0x7fffu + ((u >> 16) & 1u);
  return (uint16_t)(u >> 16);
}
__device__ __forceinline__ uint32_t pack2(float lo, float hi) {
  return (uint32_t)f2bf(lo) | ((uint32_t)f2bf(hi) << 16);
}

#define MFMA(a, b, c) __builtin_amdgcn_mfma_f32_16x16x32_bf16(a, b, c, 0, 0, 0)

// ---------------- kernel A: mix + biases (one block per sample) ----------------
__global__ void k_mix_bias(const float* __restrict__ lat,
                           const float* __restrict__ w_dyna,
                           const float* __restrict__ b_dyna,
                           const float* __restrict__ b_in_mix,
                           const float* __restrict__ b_mid_mix,
                           const float* __restrict__ b_out_mix,
                           const float* __restrict__ b_short_mix,
                           float* __restrict__ ws_mix,
                           float* __restrict__ ws_bias) {
  __shared__ float smix[NMIX];
  const int t = threadIdx.x;
  const int lane = t & 63, wv = t >> 6;
  const int b = blockIdx.x;
#pragma unroll
  for (int d2 = 0; d2 < 2; d2++) {
    int m = wv * 2 + d2;
    float s = 0.f;
#pragma unroll
    for (int j = 0; j < 8; j++)
      s += lat[b * LAT + j * 64 + lane] * w_dyna[m * LAT + j * 64 + lane];
#pragma unroll
    for (int off = 32; off; off >>= 1) s += __shfl_xor(s, off);
    if (lane == 0) {
      float v = s + b_dyna[m];
      ws_mix[b * NMIX + m] = v;
      smix[m] = v;
    }
  }
  __syncthreads();
  const float* banks[4] = {b_in_mix, b_mid_mix, b_out_mix, b_short_mix};
  for (int pos = t; pos < 1024; pos += 256) {
    int bank = pos >> 8, ch = pos & 255;
    const float* bp = banks[bank];
    float a = 0.f;
#pragma unroll
    for (int m = 0; m < NMIX; m++) a += smix[m] * bp[m * 256 + ch];
    ws_bias[(bank * B_ + b) * 256 + ch] = a;
  }
}

// ---------------- kernel B: mixed per-sample bf16 weights, FRAGMENT-PACKED ----
// (unchanged from rounds 3/4 -- passed, bit-identical packed layout)
__global__ void k_weights(const float* __restrict__ k_in_mix,
                          const float* __restrict__ k_mid_mix,
                          const float* __restrict__ k_out_mix,
                          const float* __restrict__ k_short_mix,
                          const float* __restrict__ ws_mix,
                          uint16_t* __restrict__ w_in,
                          uint16_t* __restrict__ w_mid,
                          uint16_t* __restrict__ w_out,
                          uint16_t* __restrict__ w_short) {
  __shared__ float smix[B_ * NMIX];
  const int t = threadIdx.x;
  if (t < B_ * NMIX) smix[t] = ws_mix[t];
  __syncthreads();
  const int e8 = (blockIdx.x * 256 + t) * 8;  // 8-aligned packed position
  const float* srcA;
  uint16_t* dst;
  int sstride, dstride;
  bool ileave;  // block-uniform
  if (e8 < 65536) {                       // w_in, KT=8
    int e = e8;
    int lane = (e >> 3) & 63, ots = (e >> 9) & 3, kt = (e >> 11) & 7, wv = e >> 14;
    int row = wv * 64 + ots * 16 + (lane & 15);
    int k0 = kt * 32 + (lane >> 4) * 8;
    srcA = k_in_mix + row * 256 + k0; sstride = 65536; ileave = false;
    dst = w_in + e;                   dstride = 65536;
  } else if (e8 < 196608) {               // w_mid, KT=16, sin/cos interleave
    int e = e8 - 65536;
    int lane = (e >> 3) & 63, ots = (e >> 9) & 3, kt = (e >> 11) & 15, wv = e >> 15;
    int row = wv * 64 + ots * 16 + (lane & 15);
    int kp0 = kt * 32 + (lane >> 4) * 8;       // 8-aligned -> i0 = kp0/2, 4-aligned
    srcA = k_mid_mix + row * 512 + (kp0 >> 1); sstride = 131072; ileave = true;
    dst = w_mid + e;                           dstride = 131072;
  } else if (e8 < 327680) {               // w_out, KT=16, interleave
    int e = e8 - 196608;
    int lane = (e >> 3) & 63, ots = (e >> 9) & 3, kt = (e >> 11) & 15, wv = e >> 15;
    int row = wv * 64 + ots * 16 + (lane & 15);
    int kp0 = kt * 32 + (lane >> 4) * 8;
    srcA = k_out_mix + row * 512 + (kp0 >> 1); sstride = 131072; ileave = true;
    dst = w_out + e;                           dstride = 131072;
  } else {                                // w_short, KT=8
    int e = e8 - 327680;
    int lane = (e >> 3) & 63, ots = (e >> 9) & 3, kt = (e >> 11) & 7, wv = e >> 14;
    int row = wv * 64 + ots * 16 + (lane & 15);
    int k0 = kt * 32 + (lane >> 4) * 8;
    srcA = k_short_mix + row * 256 + k0; sstride = 65536; ileave = false;
    dst = w_short + e;                   dstride = 65536;
  }
  // srcB offset: non-interleaved -> +4 (elements 4..7); interleaved -> +256 (cos half)
  const int boff = ileave ? 256 : 4;
  float4 va[NMIX], vb[NMIX];
#pragma unroll
  for (int m = 0; m < NMIX; m++) {
    va[m] = *(const float4*)(srcA + m * sstride);
    vb[m] = *(const float4*)(srcA + m * sstride + boff);
  }
  for (int b = 0; b < B_; b++) {
    float4 ra = make_float4(0.f, 0.f, 0.f, 0.f), rb = ra;
#pragma unroll
    for (int m = 0; m < NMIX; m++) {
      const float s = smix[b * NMIX + m];
      ra.x += s * va[m].x; ra.y += s * va[m].y; ra.z += s * va[m].z; ra.w += s * va[m].w;
      rb.x += s * vb[m].x; rb.y += s * vb[m].y; rb.z += s * vb[m].z; rb.w += s * vb[m].w;
    }
    int4 pkt;
    if (ileave) {  // out order: a0,b0,a1,b1,a2,b2,a3,b3  (sin/cos interleave)
      pkt = make_int4((int)pack2(ra.x, rb.x), (int)pack2(ra.y, rb.y),
                      (int)pack2(ra.z, rb.z), (int)pack2(ra.w, rb.w));
    } else {       // out order: a0,a1,a2,a3,b0,b1,b2,b3
      pkt = make_int4((int)pack2(ra.x, ra.y), (int)pack2(ra.z, ra.w),
                      (int)pack2(rb.x, rb.y), (int)pack2(rb.z, rb.w));
    }
    *(int4*)(dst + (size_t)b * dstride) = pkt;
  }
}

// ---------------- main fused kernel (v5) ----
// vs v3 (86 us best):
//  (1) X tile staged ENTIRELY up-front (32 KB bf16, [64 pos][256 ch]) into the
//      H1 region (dead during phase A; one barrier before H1 overwrite). Phase A
//      becomes a barrier-free 8-step loop -> the 7 per-step vmcnt(0) barrier
//      drains of v3 collapse to 1. LDS 72 -> 64 KB.
//  (2) phases B/C: ds ping-pong (fragment kt+1 loaded before cluster kt, +16
//      regs) PAID FOR by weight prefetch 4-buffer/3-deep -> 2-buffer ping-pong
//      issued after cluster kt (-32 regs). Net -16 vs v3: no spill (round-4
//      lesson: unified file is exactly full at 128 VGPR + 128 acc).
// Barriers: 5 total. Register budget audited to stay <= 128 arch VGPRs.
__launch_bounds__(256, 2)
__global__ void k_main(const float* __restrict__ x,
                       const float* __restrict__ ws_bias,
                       const uint16_t* __restrict__ w_in,
                       const uint16_t* __restrict__ w_mid,
                       const uint16_t* __restrict__ w_out,
                       const uint16_t* __restrict__ w_short,
                       float* __restrict__ out) {
  __shared__ int4 smem4[65536 / 16];
  char* lds = (char*)smem4;
  char* Xs = lds;            // 32768 bytes: [64 pos][256 ch] bf16, chunk-xor swz
  char* H1 = lds;            // 65536 bytes: [64 pos][512 ch] bf16 (after phase A)

  const int t = threadIdx.x;
  const int lane = t & 63;
  const int wv = t >> 6;     // 0..3
  const int q = lane >> 4;
  const int n = lane & 15;
  const int b = blockIdx.x & 15;
  const int p0 = (blockIdx.x >> 4) * MT;

  const float* xb = x + (size_t)b * FIN * HW + p0;
  const int xpos = t & 63;   // position this thread stages

  // ---- stage FULL X tile: 64 scalar loads/thread, one burst, one drain ----
  {
    float xr[8][8];
#pragma unroll
    for (int u = 0; u < 8; u++) {
      const int cg = wv * 8 + u;  // 8-channel group 0..31
#pragma unroll
      for (int e = 0; e < 8; e++)
        xr[u][e] = xb[(size_t)(cg * 8 + e) * HW + xpos];
    }
#pragma unroll
    for (int u = 0; u < 8; u++) {
      const int cg = wv * 8 + u;
      *(int4*)(Xs + xpos * 512 + ((cg ^ (xpos & 7)) * 16)) = make_int4(
          (int)pack2(xr[u][0], xr[u][1]), (int)pack2(xr[u][2], xr[u][3]),
          (int)pack2(xr[u][4], xr[u][5]), (int)pack2(xr[u][6], xr[u][7]));
    }
  }

  // ---- phase A accumulator init: h = b_in, s = b_short ----
  f32x4 acc_h[4][4], acc_s[4][4];
#pragma unroll
  for (int ots = 0; ots < 4; ots++) {
    const int o = wv * 64 + ots * 16 + q * 4;
    const float4 vi = *(const float4*)&ws_bias[(0 * B_ + b) * 256 + o];
    const float4 vs = *(const float4*)&ws_bias[(3 * B_ + b) * 256 + o];
    f32x4 ah, asv;
    ah[0] = vi.x; ah[1] = vi.y; ah[2] = vi.z; ah[3] = vi.w;
    asv[0] = vs.x; asv[1] = vs.y; asv[2] = vs.z; asv[3] = vs.w;
#pragma unroll
    for (int pt = 0; pt < 4; pt++) { acc_h[ots][pt] = ah; acc_s[ots][pt] = asv; }
  }

  // phase-A weight prefetch (kt=0), issued before the barrier
  const uint16_t* Wi = w_in + (size_t)b * 65536 + wv * 16384 + lane * 8;
  const uint16_t* Ws = w_short + (size_t)b * 65536 + wv * 16384 + lane * 8;
  bf16x8 ai[2][4], asf[2][4];
#pragma unroll
  for (int ots = 0; ots < 4; ots++) {
    ai[0][ots] = *(const bf16x8*)(Wi + ots * 512);
    asf[0][ots] = *(const bf16x8*)(Ws + ots * 512);
  }
  __syncthreads();  // bar1: X staged (single vmcnt drain for all of X)

  // ---- phase A: h1 = K_in @ X + b_in ; short = K_short @ X + b_short ----
  // Barrier-free 8-step loop; 1-ahead weight ping-pong.
#pragma unroll
  for (int kt = 0; kt < 8; kt++) {
    if (kt < 7) {
#pragma unroll
      for (int ots = 0; ots < 4; ots++) {
        ai[(kt + 1) & 1][ots] = *(const bf16x8*)(Wi + (kt + 1) * 2048 + ots * 512);
        asf[(kt + 1) & 1][ots] = *(const bf16x8*)(Ws + (kt + 1) * 2048 + ots * 512);
      }
    }
    bf16x8 bf[4];
#pragma unroll
    for (int pt = 0; pt < 4; pt++) {
      const int p = pt * 16 + n;
      bf[pt] = *(const bf16x8*)(Xs + p * 512 + (((kt * 4 + q) ^ (p & 7)) * 16));
    }
    __builtin_amdgcn_s_setprio(1);
#pragma unroll
    for (int ots = 0; ots < 4; ots++) {
#pragma unroll
      for (int pt = 0; pt < 4; pt++) {
        acc_h[ots][pt] = MFMA(ai[kt & 1][ots], bf[pt], acc_h[ots][pt]);
        acc_s[ots][pt] = MFMA(asf[kt & 1][ots], bf[pt], acc_s[ots][pt]);
      }
    }
    __builtin_amdgcn_s_setprio(0);
  }
  __syncthreads();  // bar2: all X reads done before H1 overwrites the region

  // ---- complex_wave(h1) -> H1 (k' = 2*o + {0:sin,1:cos}, ctile-xor swizzle) ----
#pragma unroll
  for (int ots = 0; ots < 4; ots++) {
    const int ctile = (wv * 4 + ots) * 4 + q;
#pragma unroll
    for (int pt = 0; pt < 4; pt++) {
      const int p = pt * 16 + n;
      *(int4*)(H1 + p * 1024 + ((ctile ^ (p & 7)) * 16)) = make_int4(
          (int)pack2(__sinf(acc_h[ots][pt][0]), __cosf(acc_h[ots][pt][0])),
          (int)pack2(__sinf(acc_h[ots][pt][1]), __cosf(acc_h[ots][pt][1])),
          (int)pack2(__sinf(acc_h[ots][pt][2]), __cosf(acc_h[ots][pt][2])),
          (int)pack2(__sinf(acc_h[ots][pt][3]), __cosf(acc_h[ots][pt][3])));
    }
  }

  // phase-B prologue: bias init + 2 weight buffers, issued before the barrier
  const uint16_t* Wm = w_mid + (size_t)b * 131072 + wv * 32768 + lane * 8;
  bf16x8 am[2][4];
#pragma unroll
  for (int ots = 0; ots < 4; ots++) {
    am[0][ots] = *(const bf16x8*)(Wm + 0 * 2048 + ots * 512);
    am[1][ots] = *(const bf16x8*)(Wm + 1 * 2048 + ots * 512);
  }
  f32x4 acc2[4][4];
#pragma unroll
  for (int ots = 0; ots < 4; ots++) {
    const int o = wv * 64 + ots * 16 + q * 4;
    const float4 v = *(const float4*)&ws_bias[(1 * B_ + b) * 256 + o];
    f32x4 a2;
    a2[0] = v.x; a2[1] = v.y; a2[2] = v.z; a2[3] = v.w;
#pragma unroll
    for (int pt = 0; pt < 4; pt++) acc2[ots][pt] = a2;
  }
  __syncthreads();  // bar3: H1 writes visible to all waves

  // ---- phase B: h2 = K_mid(perm) @ H1c + b_mid ----
  // ds ping-pong (kt+1 fragments loaded before cluster kt); weight loads for
  // kt+2 issued AFTER cluster kt (full-iteration latency cover, WAR-safe).
  {
    bf16x8 bfP[2][4];
#pragma unroll
    for (int pt = 0; pt < 4; pt++) {
      const int p = pt * 16 + n;
      bfP[0][pt] = *(const bf16x8*)(H1 + p * 1024 + ((q ^ (p & 7)) * 16));
    }
#pragma unroll
    for (int kt = 0; kt < 16; kt++) {
      if (kt < 15) {
#pragma unroll
        for (int pt = 0; pt < 4; pt++) {
          const int p = pt * 16 + n;
          bfP[(kt + 1) & 1][pt] =
              *(const bf16x8*)(H1 + p * 1024 + ((((kt + 1) * 4 + q) ^ (p & 7)) * 16));
        }
      }
      __builtin_amdgcn_s_setprio(1);
#pragma unroll
      for (int ots = 0; ots < 4; ots++)
#pragma unroll
        for (int pt = 0; pt < 4; pt++)
          acc2[ots][pt] = MFMA(am[kt & 1][ots], bfP[kt & 1][pt], acc2[ots][pt]);
      __builtin_amdgcn_s_setprio(0);
      if (kt < 14) {
#pragma unroll
        for (int ots = 0; ots < 4; ots++)
          am[kt & 1][ots] = *(const bf16x8*)(Wm + (kt + 2) * 2048 + ots * 512);
      }
    }
  }
  __syncthreads();  // bar4: all H1 reads done before overwrite

  // ---- complex_wave(h2) -> H2 (overlays H1 region) ----
#pragma unroll
  for (int ots = 0; ots < 4; ots++) {
    const int ctile = (wv * 4 + ots) * 4 + q;
#pragma unroll
    for (int pt = 0; pt < 4; pt++) {
      const int p = pt * 16 + n;
      *(int4*)(H1 + p * 1024 + ((ctile ^ (p & 7)) * 16)) = make_int4(
          (int)pack2(__sinf(acc2[ots][pt][0]), __cosf(acc2[ots][pt][0])),
          (int)pack2(__sinf(acc2[ots][pt][1]), __cosf(acc2[ots][pt][1])),
          (int)pack2(__sinf(acc2[ots][pt][2]), __cosf(acc2[ots][pt][2])),
          (int)pack2(__sinf(acc2[ots][pt][3]), __cosf(acc2[ots][pt][3])));
    }
  }

  // phase-C prologue: acc3 = short + b_out (in place in acc_s) + 2 weight bufs
  const uint16_t* Wo = w_out + (size_t)b * 131072 + wv * 32768 + lane * 8;
  bf16x8 ao[2][4];
#pragma unroll
  for (int ots = 0; ots < 4; ots++) {
    ao[0][ots] = *(const bf16x8*)(Wo + 0 * 2048 + ots * 512);
    ao[1][ots] = *(const bf16x8*)(Wo + 1 * 2048 + ots * 512);
  }
#pragma unroll
  for (int ots = 0; ots < 4; ots++) {
    const int o = wv * 64 + ots * 16 + q * 4;
    const float4 v = *(const float4*)&ws_bias[(2 * B_ + b) * 256 + o];
#pragma unroll
    for (int pt = 0; pt < 4; pt++) {
      acc_s[ots][pt][0] += v.x; acc_s[ots][pt][1] += v.y;
      acc_s[ots][pt][2] += v.z; acc_s[ots][pt][3] += v.w;
    }
  }
  __syncthreads();  // bar5: H2 writes visible

  // ---- phase C: out = K_out(perm) @ H2c + b_out + short ----
  {
    bf16x8 bfP[2][4];
#pragma unroll
    for (int pt = 0; pt < 4; pt++) {
      const int p = pt * 16 + n;
      bfP[0][pt] = *(const bf16x8*)(H1 + p * 1024 + ((q ^ (p & 7)) * 16));
    }
#pragma unroll
    for (int kt = 0; kt < 16; kt++) {
      if (kt < 15) {
#pragma unroll
        for (int pt = 0; pt < 4; pt++) {
          const int p = pt * 16 + n;
          bfP[(kt + 1) & 1][pt] =
              *(const bf16x8*)(H1 + p * 1024 + ((((kt + 1) * 4 + q) ^ (p & 7)) * 16));
        }
      }
      __builtin_amdgcn_s_setprio(1);
#pragma unroll
      for (int ots = 0; ots < 4; ots++)
#pragma unroll
        for (int pt = 0; pt < 4; pt++)
          acc_s[ots][pt] = MFMA(ao[kt & 1][ots], bfP[kt & 1][pt], acc_s[ots][pt]);
      __builtin_amdgcn_s_setprio(0);
      if (kt < 14) {
#pragma unroll
        for (int ots = 0; ots < 4; ots++)
          ao[kt & 1][ots] = *(const bf16x8*)(Wo + (kt + 2) * 2048 + ots * 512);
      }
    }
  }

  // ---- store ----
  {
    float* ob = out + (size_t)b * FOUT * HW + p0;
#pragma unroll
    for (int ots = 0; ots < 4; ots++) {
#pragma unroll
      for (int pt = 0; pt < 4; pt++) {
#pragma unroll
        for (int r = 0; r < 4; r++) {
          const int o = wv * 64 + ots * 16 + q * 4 + r;
          ob[(size_t)o * HW + pt * 16 + n] = acc_s[ots][pt][r];
        }
      }
    }
  }
}

extern "C" void kernel_launch(void* const* d_in, const int* in_sizes, int n_in,
                              void* d_out, int out_size, void* d_ws, size_t ws_size,
                              hipStream_t stream) {
  const float* x           = (const float*)d_in[0];
  const float* lat         = (const float*)d_in[1];
  const float* k_in_mix    = (const float*)d_in[2];
  const float* k_mid_mix   = (const float*)d_in[3];
  const float* k_out_mix   = (const float*)d_in[4];
  const float* k_short_mix = (const float*)d_in[5];
  const float* b_in_mix    = (const float*)d_in[6];
  const float* b_mid_mix   = (const float*)d_in[7];
  const float* b_out_mix   = (const float*)d_in[8];
  const float* b_short_mix = (const float*)d_in[9];
  const float* w_dyna      = (const float*)d_in[10];
  const float* b_dyna      = (const float*)d_in[11];

  char* ws = (char*)d_ws;
  float*    ws_mix  = (float*)(ws + WS_MIX);
  float*    ws_bias = (float*)(ws + WS_BIAS);
  uint16_t* w_in    = (uint16_t*)(ws + WS_WIN);
  uint16_t* w_mid   = (uint16_t*)(ws + WS_WMID);
  uint16_t* w_out   = (uint16_t*)(ws + WS_WOUT);
  uint16_t* w_short = (uint16_t*)(ws + WS_WSHORT);
  float* out = (float*)d_out;

  hipLaunchKernelGGL(k_mix_bias, dim3(16), dim3(256), 0, stream,
                     lat, w_dyna, b_dyna, b_in_mix, b_mid_mix, b_out_mix,
                     b_short_mix, ws_mix, ws_bias);
  hipLaunchKernelGGL(k_weights, dim3(192), dim3(256), 0, stream,
                     k_in_mix, k_mid_mix, k_out_mix, k_short_mix, ws_mix,
                     w_in, w_mid, w_out, w_short);
  hipLaunchKernelGGL(k_main, dim3(1024), dim3(256), 0, stream,
                     x, ws_bias, w_in, w_mid, w_out, w_short, out);
}

// Round 7
// 190.269 us; speedup vs baseline: 1.1186x; 1.0004x over previous
//
#include <hip/hip_runtime.h>
#include <stdint.h>

#define B_    16
#define FIN   256
#define FOUT  256
#define FH2   256
#define NMIX  8
#define LAT   512
#define HW    4096
#define MT    64

typedef short bf16x8 __attribute__((ext_vector_type(8)));
typedef float f32x4  __attribute__((ext_vector_type(4)));

// workspace layout (bytes) -- unchanged
#define WS_MIX    0           // [16][8] f32
#define WS_BIAS   1024        // [4][16][256] f32 : in, mid, out, short
#define WS_WIN    131072      // [16][65536] bf16, fragment-packed
#define WS_WMID   2228224     // [16][131072] bf16, fragment-packed (sin/cos interleaved k')
#define WS_WOUT   6422528     // [16][131072] bf16, fragment-packed
#define WS_WSHORT 10616832    // [16][65536] bf16, fragment-packed

// RNE f32->bf16, bit-twiddle (PROVEN bits; round-6 lesson: v_cvt_pk_bf16_f32 is
// NOT bit-identical -- absmax blew up 26x. Do not substitute without ISA-level
// rounding proof.)
__device__ __forceinline__ uint16_t f2bf(float f) {
  uint32_t u = __builtin_bit_cast(uint32_t, f);
  u += 0x7fffu + ((u >> 16) & 1u);
  return (uint16_t)(u >> 16);
}
__device__ __forceinline__ uint32_t pack2(float lo, float hi) {
  return (uint32_t)f2bf(lo) | ((uint32_t)f2bf(hi) << 16);
}

#define MFMA(a, b, c) __builtin_amdgcn_mfma_f32_16x16x32_bf16(a, b, c, 0, 0, 0)

// ---------------- kernel A: mix + biases (one block per sample) ----------------
__global__ void k_mix_bias(const float* __restrict__ lat,
                           const float* __restrict__ w_dyna,
                           const float* __restrict__ b_dyna,
                           const float* __restrict__ b_in_mix,
                           const float* __restrict__ b_mid_mix,
                           const float* __restrict__ b_out_mix,
                           const float* __restrict__ b_short_mix,
                           float* __restrict__ ws_mix,
                           float* __restrict__ ws_bias) {
  __shared__ float smix[NMIX];
  const int t = threadIdx.x;
  const int lane = t & 63, wv = t >> 6;
  const int b = blockIdx.x;
#pragma unroll
  for (int d2 = 0; d2 < 2; d2++) {
    int m = wv * 2 + d2;
    float s = 0.f;
#pragma unroll
    for (int j = 0; j < 8; j++)
      s += lat[b * LAT + j * 64 + lane] * w_dyna[m * LAT + j * 64 + lane];
#pragma unroll
    for (int off = 32; off; off >>= 1) s += __shfl_xor(s, off);
    if (lane == 0) {
      float v = s + b_dyna[m];
      ws_mix[b * NMIX + m] = v;
      smix[m] = v;
    }
  }
  __syncthreads();
  const float* banks[4] = {b_in_mix, b_mid_mix, b_out_mix, b_short_mix};
  for (int pos = t; pos < 1024; pos += 256) {
    int bank = pos >> 8, ch = pos & 255;
    const float* bp = banks[bank];
    float a = 0.f;
#pragma unroll
    for (int m = 0; m < NMIX; m++) a += smix[m] * bp[m * 256 + ch];
    ws_bias[(bank * B_ + b) * 256 + ch] = a;
  }
}

// ---------------- kernel B: mixed per-sample bf16 weights, FRAGMENT-PACKED ----
// (structure from rounds 3-5, f2bf bits identical to all passing rounds)
__global__ void k_weights(const float* __restrict__ k_in_mix,
                          const float* __restrict__ k_mid_mix,
                          const float* __restrict__ k_out_mix,
                          const float* __restrict__ k_short_mix,
                          const float* __restrict__ ws_mix,
                          uint16_t* __restrict__ w_in,
                          uint16_t* __restrict__ w_mid,
                          uint16_t* __restrict__ w_out,
                          uint16_t* __restrict__ w_short) {
  __shared__ float smix[B_ * NMIX];
  const int t = threadIdx.x;
  if (t < B_ * NMIX) smix[t] = ws_mix[t];
  __syncthreads();
  const int e8 = (blockIdx.x * 256 + t) * 8;  // 8-aligned packed position
  const float* srcA;
  uint16_t* dst;
  int sstride, dstride;
  bool ileave;  // block-uniform
  if (e8 < 65536) {                       // w_in, KT=8
    int e = e8;
    int lane = (e >> 3) & 63, ots = (e >> 9) & 3, kt = (e >> 11) & 7, wv = e >> 14;
    int row = wv * 64 + ots * 16 + (lane & 15);
    int k0 = kt * 32 + (lane >> 4) * 8;
    srcA = k_in_mix + row * 256 + k0; sstride = 65536; ileave = false;
    dst = w_in + e;                   dstride = 65536;
  } else if (e8 < 196608) {               // w_mid, KT=16, sin/cos interleave
    int e = e8 - 65536;
    int lane = (e >> 3) & 63, ots = (e >> 9) & 3, kt = (e >> 11) & 15, wv = e >> 15;
    int row = wv * 64 + ots * 16 + (lane & 15);
    int kp0 = kt * 32 + (lane >> 4) * 8;       // 8-aligned -> i0 = kp0/2, 4-aligned
    srcA = k_mid_mix + row * 512 + (kp0 >> 1); sstride = 131072; ileave = true;
    dst = w_mid + e;                           dstride = 131072;
  } else if (e8 < 327680) {               // w_out, KT=16, interleave
    int e = e8 - 196608;
    int lane = (e >> 3) & 63, ots = (e >> 9) & 3, kt = (e >> 11) & 15, wv = e >> 15;
    int row = wv * 64 + ots * 16 + (lane & 15);
    int kp0 = kt * 32 + (lane >> 4) * 8;
    srcA = k_out_mix + row * 512 + (kp0 >> 1); sstride = 131072; ileave = true;
    dst = w_out + e;                           dstride = 131072;
  } else {                                // w_short, KT=8
    int e = e8 - 327680;
    int lane = (e >> 3) & 63, ots = (e >> 9) & 3, kt = (e >> 11) & 7, wv = e >> 14;
    int row = wv * 64 + ots * 16 + (lane & 15);
    int k0 = kt * 32 + (lane >> 4) * 8;
    srcA = k_short_mix + row * 256 + k0; sstride = 65536; ileave = false;
    dst = w_short + e;                   dstride = 65536;
  }
  // srcB offset: non-interleaved -> +4 (elements 4..7); interleaved -> +256 (cos half)
  const int boff = ileave ? 256 : 4;
  float4 va[NMIX], vb[NMIX];
#pragma unroll
  for (int m = 0; m < NMIX; m++) {
    va[m] = *(const float4*)(srcA + m * sstride);
    vb[m] = *(const float4*)(srcA + m * sstride + boff);
  }
  for (int b = 0; b < B_; b++) {
    float4 ra = make_float4(0.f, 0.f, 0.f, 0.f), rb = ra;
#pragma unroll
    for (int m = 0; m < NMIX; m++) {
      const float s = smix[b * NMIX + m];
      ra.x += s * va[m].x; ra.y += s * va[m].y; ra.z += s * va[m].z; ra.w += s * va[m].w;
      rb.x += s * vb[m].x; rb.y += s * vb[m].y; rb.z += s * vb[m].z; rb.w += s * vb[m].w;
    }
    int4 pkt;
    if (ileave) {  // out order: a0,b0,a1,b1,a2,b2,a3,b3  (sin/cos interleave)
      pkt = make_int4((int)pack2(ra.x, rb.x), (int)pack2(ra.y, rb.y),
                      (int)pack2(ra.z, rb.z), (int)pack2(ra.w, rb.w));
    } else {       // out order: a0,a1,a2,a3,b0,b1,b2,b3
      pkt = make_int4((int)pack2(ra.x, ra.y), (int)pack2(ra.z, ra.w),
                      (int)pack2(rb.x, rb.y), (int)pack2(rb.z, rb.w));
    }
    *(int4*)(dst + (size_t)b * dstride) = pkt;
  }
}

// ---------------- main fused kernel (v7 = v6 schedule + proven f2bf bits) ----
// vs v5 (73.5 us):
//  (1) phase A: weight prefetch distance 2, issued AFTER the MFMA cluster
//      (cover ~1.8 clusters vs <1 before); same register count.
//  (2) phases B/C: weight triple-buffer am[3]/ao[3], distance 3 issued after
//      cluster (+16 regs; peak pipeline regs = 80 = v3's proven no-spill level).
// Spill guard: WRITE_SIZE must stay ~65.5 MB, VGPR_Count 128.
__launch_bounds__(256, 2)
__global__ void k_main(const float* __restrict__ x,
                       const float* __restrict__ ws_bias,
                       const uint16_t* __restrict__ w_in,
                       const uint16_t* __restrict__ w_mid,
                       const uint16_t* __restrict__ w_out,
                       const uint16_t* __restrict__ w_short,
                       float* __restrict__ out) {
  __shared__ int4 smem4[65536 / 16];
  char* lds = (char*)smem4;
  char* Xs = lds;            // 32768 bytes: [64 pos][256 ch] bf16, chunk-xor swz
  char* H1 = lds;            // 65536 bytes: [64 pos][512 ch] bf16 (after phase A)

  const int t = threadIdx.x;
  const int lane = t & 63;
  const int wv = t >> 6;     // 0..3
  const int q = lane >> 4;
  const int n = lane & 15;
  const int b = blockIdx.x & 15;
  const int p0 = (blockIdx.x >> 4) * MT;

  const float* xb = x + (size_t)b * FIN * HW + p0;
  const int xpos = t & 63;   // position this thread stages

  // ---- stage FULL X tile: 64 scalar loads/thread, one burst, one drain ----
  {
    float xr[8][8];
#pragma unroll
    for (int u = 0; u < 8; u++) {
      const int cg = wv * 8 + u;  // 8-channel group 0..31
#pragma unroll
      for (int e = 0; e < 8; e++)
        xr[u][e] = xb[(size_t)(cg * 8 + e) * HW + xpos];
    }
#pragma unroll
    for (int u = 0; u < 8; u++) {
      const int cg = wv * 8 + u;
      *(int4*)(Xs + xpos * 512 + ((cg ^ (xpos & 7)) * 16)) = make_int4(
          (int)pack2(xr[u][0], xr[u][1]), (int)pack2(xr[u][2], xr[u][3]),
          (int)pack2(xr[u][4], xr[u][5]), (int)pack2(xr[u][6], xr[u][7]));
    }
  }

  // ---- phase A accumulator init: h = b_in, s = b_short ----
  f32x4 acc_h[4][4], acc_s[4][4];
#pragma unroll
  for (int ots = 0; ots < 4; ots++) {
    const int o = wv * 64 + ots * 16 + q * 4;
    const float4 vi = *(const float4*)&ws_bias[(0 * B_ + b) * 256 + o];
    const float4 vs = *(const float4*)&ws_bias[(3 * B_ + b) * 256 + o];
    f32x4 ah, asv;
    ah[0] = vi.x; ah[1] = vi.y; ah[2] = vi.z; ah[3] = vi.w;
    asv[0] = vs.x; asv[1] = vs.y; asv[2] = vs.z; asv[3] = vs.w;
#pragma unroll
    for (int pt = 0; pt < 4; pt++) { acc_h[ots][pt] = ah; acc_s[ots][pt] = asv; }
  }

  // phase-A weight prefetch: kt=0 -> buf0, kt=1 -> buf1, before the barrier
  const uint16_t* Wi = w_in + (size_t)b * 65536 + wv * 16384 + lane * 8;
  const uint16_t* Ws = w_short + (size_t)b * 65536 + wv * 16384 + lane * 8;
  bf16x8 ai[2][4], asf[2][4];
#pragma unroll
  for (int ots = 0; ots < 4; ots++) {
    ai[0][ots] = *(const bf16x8*)(Wi + 0 * 2048 + ots * 512);
    asf[0][ots] = *(const bf16x8*)(Ws + 0 * 2048 + ots * 512);
    ai[1][ots] = *(const bf16x8*)(Wi + 1 * 2048 + ots * 512);
    asf[1][ots] = *(const bf16x8*)(Ws + 1 * 2048 + ots * 512);
  }
  __syncthreads();  // bar1: X staged (single vmcnt drain for all of X)

  // ---- phase A: h1 = K_in @ X + b_in ; short = K_short @ X + b_short ----
  // Barrier-free; weight loads for kt+2 issued AFTER cluster kt (dist 2).
#pragma unroll
  for (int kt = 0; kt < 8; kt++) {
    bf16x8 bf[4];
#pragma unroll
    for (int pt = 0; pt < 4; pt++) {
      const int p = pt * 16 + n;
      bf[pt] = *(const bf16x8*)(Xs + p * 512 + (((kt * 4 + q) ^ (p & 7)) * 16));
    }
    __builtin_amdgcn_s_setprio(1);
#pragma unroll
    for (int ots = 0; ots < 4; ots++) {
#pragma unroll
      for (int pt = 0; pt < 4; pt++) {
        acc_h[ots][pt] = MFMA(ai[kt & 1][ots], bf[pt], acc_h[ots][pt]);
        acc_s[ots][pt] = MFMA(asf[kt & 1][ots], bf[pt], acc_s[ots][pt]);
      }
    }
    __builtin_amdgcn_s_setprio(0);
    if (kt < 6) {  // refill the buffer just consumed with kt+2
#pragma unroll
      for (int ots = 0; ots < 4; ots++) {
        ai[kt & 1][ots] = *(const bf16x8*)(Wi + (kt + 2) * 2048 + ots * 512);
        asf[kt & 1][ots] = *(const bf16x8*)(Ws + (kt + 2) * 2048 + ots * 512);
      }
    }
  }
  __syncthreads();  // bar2: all X reads done before H1 overwrites the region

  // ---- complex_wave(h1) -> H1 (k' = 2*o + {0:sin,1:cos}, ctile-xor swizzle) ----
#pragma unroll
  for (int ots = 0; ots < 4; ots++) {
    const int ctile = (wv * 4 + ots) * 4 + q;
#pragma unroll
    for (int pt = 0; pt < 4; pt++) {
      const int p = pt * 16 + n;
      *(int4*)(H1 + p * 1024 + ((ctile ^ (p & 7)) * 16)) = make_int4(
          (int)pack2(__sinf(acc_h[ots][pt][0]), __cosf(acc_h[ots][pt][0])),
          (int)pack2(__sinf(acc_h[ots][pt][1]), __cosf(acc_h[ots][pt][1])),
          (int)pack2(__sinf(acc_h[ots][pt][2]), __cosf(acc_h[ots][pt][2])),
          (int)pack2(__sinf(acc_h[ots][pt][3]), __cosf(acc_h[ots][pt][3])));
    }
  }

  // phase-B prologue: bias init + 3 weight buffers (kt 0,1,2), before barrier
  const uint16_t* Wm = w_mid + (size_t)b * 131072 + wv * 32768 + lane * 8;
  bf16x8 am[3][4];
#pragma unroll
  for (int ots = 0; ots < 4; ots++) {
    am[0][ots] = *(const bf16x8*)(Wm + 0 * 2048 + ots * 512);
    am[1][ots] = *(const bf16x8*)(Wm + 1 * 2048 + ots * 512);
    am[2][ots] = *(const bf16x8*)(Wm + 2 * 2048 + ots * 512);
  }
  f32x4 acc2[4][4];
#pragma unroll
  for (int ots = 0; ots < 4; ots++) {
    const int o = wv * 64 + ots * 16 + q * 4;
    const float4 v = *(const float4*)&ws_bias[(1 * B_ + b) * 256 + o];
    f32x4 a2;
    a2[0] = v.x; a2[1] = v.y; a2[2] = v.z; a2[3] = v.w;
#pragma unroll
    for (int pt = 0; pt < 4; pt++) acc2[ots][pt] = a2;
  }
  __syncthreads();  // bar3: H1 writes visible to all waves

  // ---- phase B: h2 = K_mid(perm) @ H1c + b_mid ----
  // ds ping-pong (kt+1 fragments before cluster kt); weight loads for kt+3
  // issued AFTER cluster kt into the just-freed buffer (distance 3).
  {
    bf16x8 bfP[2][4];
#pragma unroll
    for (int pt = 0; pt < 4; pt++) {
      const int p = pt * 16 + n;
      bfP[0][pt] = *(const bf16x8*)(H1 + p * 1024 + ((q ^ (p & 7)) * 16));
    }
#pragma unroll
    for (int kt = 0; kt < 16; kt++) {
      if (kt < 15) {
#pragma unroll
        for (int pt = 0; pt < 4; pt++) {
          const int p = pt * 16 + n;
          bfP[(kt + 1) & 1][pt] =
              *(const bf16x8*)(H1 + p * 1024 + ((((kt + 1) * 4 + q) ^ (p & 7)) * 16));
        }
      }
      __builtin_amdgcn_s_setprio(1);
#pragma unroll
      for (int ots = 0; ots < 4; ots++)
#pragma unroll
        for (int pt = 0; pt < 4; pt++)
          acc2[ots][pt] = MFMA(am[kt % 3][ots], bfP[kt & 1][pt], acc2[ots][pt]);
      __builtin_amdgcn_s_setprio(0);
      if (kt < 13) {
#pragma unroll
        for (int ots = 0; ots < 4; ots++)
          am[kt % 3][ots] = *(const bf16x8*)(Wm + (kt + 3) * 2048 + ots * 512);
      }
    }
  }
  __syncthreads();  // bar4: all H1 reads done before overwrite

  // ---- complex_wave(h2) -> H2 (overlays H1 region) ----
#pragma unroll
  for (int ots = 0; ots < 4; ots++) {
    const int ctile = (wv * 4 + ots) * 4 + q;
#pragma unroll
    for (int pt = 0; pt < 4; pt++) {
      const int p = pt * 16 + n;
      *(int4*)(H1 + p * 1024 + ((ctile ^ (p & 7)) * 16)) = make_int4(
          (int)pack2(__sinf(acc2[ots][pt][0]), __cosf(acc2[ots][pt][0])),
          (int)pack2(__sinf(acc2[ots][pt][1]), __cosf(acc2[ots][pt][1])),
          (int)pack2(__sinf(acc2[ots][pt][2]), __cosf(acc2[ots][pt][2])),
          (int)pack2(__sinf(acc2[ots][pt][3]), __cosf(acc2[ots][pt][3])));
    }
  }

  // phase-C prologue: acc3 = short + b_out (in place in acc_s) + 3 weight bufs
  const uint16_t* Wo = w_out + (size_t)b * 131072 + wv * 32768 + lane * 8;
  bf16x8 ao[3][4];
#pragma unroll
  for (int ots = 0; ots < 4; ots++) {
    ao[0][ots] = *(const bf16x8*)(Wo + 0 * 2048 + ots * 512);
    ao[1][ots] = *(const bf16x8*)(Wo + 1 * 2048 + ots * 512);
    ao[2][ots] = *(const bf16x8*)(Wo + 2 * 2048 + ots * 512);
  }
#pragma unroll
  for (int ots = 0; ots < 4; ots++) {
    const int o = wv * 64 + ots * 16 + q * 4;
    const float4 v = *(const float4*)&ws_bias[(2 * B_ + b) * 256 + o];
#pragma unroll
    for (int pt = 0; pt < 4; pt++) {
      acc_s[ots][pt][0] += v.x; acc_s[ots][pt][1] += v.y;
      acc_s[ots][pt][2] += v.z; acc_s[ots][pt][3] += v.w;
    }
  }
  __syncthreads();  // bar5: H2 writes visible

  // ---- phase C: out = K_out(perm) @ H2c + b_out + short ----
  {
    bf16x8 bfP[2][4];
#pragma unroll
    for (int pt = 0; pt < 4; pt++) {
      const int p = pt * 16 + n;
      bfP[0][pt] = *(const bf16x8*)(H1 + p * 1024 + ((q ^ (p & 7)) * 16));
    }
#pragma unroll
    for (int kt = 0; kt < 16; kt++) {
      if (kt < 15) {
#pragma unroll
        for (int pt = 0; pt < 4; pt++) {
          const int p = pt * 16 + n;
          bfP[(kt + 1) & 1][pt] =
              *(const bf16x8*)(H1 + p * 1024 + ((((kt + 1) * 4 + q) ^ (p & 7)) * 16));
        }
      }
      __builtin_amdgcn_s_setprio(1);
#pragma unroll
      for (int ots = 0; ots < 4; ots++)
#pragma unroll
        for (int pt = 0; pt < 4; pt++)
          acc_s[ots][pt] = MFMA(ao[kt % 3][ots], bfP[kt & 1][pt], acc_s[ots][pt]);
      __builtin_amdgcn_s_setprio(0);
      if (kt < 13) {
#pragma unroll
        for (int ots = 0; ots < 4; ots++)
          ao[kt % 3][ots] = *(const bf16x8*)(Wo + (kt + 3) * 2048 + ots * 512);
      }
    }
  }

  // ---- store ----
  {
    float* ob = out + (size_t)b * FOUT * HW + p0;
#pragma unroll
    for (int ots = 0; ots < 4; ots++) {
#pragma unroll
      for (int pt = 0; pt < 4; pt++) {
#pragma unroll
        for (int r = 0; r < 4; r++) {
          const int o = wv * 64 + ots * 16 + q * 4 + r;
          ob[(size_t)o * HW + pt * 16 + n] = acc_s[ots][pt][r];
        }
      }
    }
  }
}

extern "C" void kernel_launch(void* const* d_in, const int* in_sizes, int n_in,
                              void* d_out, int out_size, void* d_ws, size_t ws_size,
                              hipStream_t stream) {
  const float* x           = (const float*)d_in[0];
  const float* lat         = (const float*)d_in[1];
  const float* k_in_mix    = (const float*)d_in[2];
  const float* k_mid_mix   = (const float*)d_in[3];
  const float* k_out_mix   = (const float*)d_in[4];
  const float* k_short_mix = (const float*)d_in[5];
  const float* b_in_mix    = (const float*)d_in[6];
  const float* b_mid_mix   = (const float*)d_in[7];
  const float* b_out_mix   = (const float*)d_in[8];
  const float* b_short_mix = (const float*)d_in[9];
  const float* w_dyna      = (const float*)d_in[10];
  const float* b_dyna      = (const float*)d_in[11];

  char* ws = (char*)d_ws;
  float*    ws_mix  = (float*)(ws + WS_MIX);
  float*    ws_bias = (float*)(ws + WS_BIAS);
  uint16_t* w_in    = (uint16_t*)(ws + WS_WIN);
  uint16_t* w_mid   = (uint16_t*)(ws + WS_WMID);
  uint16_t* w_out   = (uint16_t*)(ws + WS_WOUT);
  uint16_t* w_short = (uint16_t*)(ws + WS_WSHORT);
  float* out = (float*)d_out;

  hipLaunchKernelGGL(k_mix_bias, dim3(16), dim3(256), 0, stream,
                     lat, w_dyna, b_dyna, b_in_mix, b_mid_mix, b_out_mix,
                     b_short_mix, ws_mix, ws_bias);
  hipLaunchKernelGGL(k_weights, dim3(192), dim3(256), 0, stream,
                     k_in_mix, k_mid_mix, k_out_mix, k_short_mix, ws_mix,
                     w_in, w_mid, w_out, w_short);
  hipLaunchKernelGGL(k_main, dim3(1024), dim3(256), 0, stream,
                     x, ws_bias, w_in, w_mid, w_out, w_short, out);
}